// Round 1
// baseline (414.637 us; speedup 1.0000x reference)
//
#include <hip/hip_runtime.h>
#include <cstdint>
#include <cstddef>

typedef unsigned short u16;
typedef __attribute__((ext_vector_type(8))) short short8;
typedef __attribute__((ext_vector_type(4))) float f32x4;
typedef __attribute__((ext_vector_type(4))) unsigned short us4;

#define AS1 __attribute__((address_space(1)))
#define AS3 __attribute__((address_space(3)))

__device__ __forceinline__ u16 f2bf(float f) {
  union { float f; unsigned u; } v; v.f = f;
  unsigned r = v.u + 0x7fffu + ((v.u >> 16) & 1u);
  return (u16)(r >> 16);
}

__device__ __forceinline__ void gload_lds16(const u16* g, u16* l) {
  __builtin_amdgcn_global_load_lds((AS1 void*)g, (AS3 void*)l, 16, 0, 0);
}

// ---------------- LayerNorm + cast to bf16 (token-major) ----------------
// one wave per token (512 elems), 4 tokens per 256-thread block
__global__ void ln_cast_kernel(const float* __restrict__ x, const float* __restrict__ g,
                               const float* __restrict__ b, u16* __restrict__ out) {
  const int lane = threadIdx.x & 63;
  const int tok = blockIdx.x * 4 + (threadIdx.x >> 6);
  const float4* row = (const float4*)(x + (size_t)tok * 512);
  float4 v0 = row[lane];
  float4 v1 = row[lane + 64];
  float s = v0.x + v0.y + v0.z + v0.w + v1.x + v1.y + v1.z + v1.w;
  float q = v0.x*v0.x + v0.y*v0.y + v0.z*v0.z + v0.w*v0.w
          + v1.x*v1.x + v1.y*v1.y + v1.z*v1.z + v1.w*v1.w;
#pragma unroll
  for (int m = 1; m < 64; m <<= 1) { s += __shfl_xor(s, m, 64); q += __shfl_xor(q, m, 64); }
  const float mean = s * (1.0f / 512.0f);
  const float var = q * (1.0f / 512.0f) - mean * mean;
  const float r = rsqrtf(var + 1e-5f);
  const float4* g4 = (const float4*)g;
  const float4* b4 = (const float4*)b;
  float4 ga = g4[lane], gb = g4[lane + 64];
  float4 ba = b4[lane], bb = b4[lane + 64];
  us4 o0 = { f2bf((v0.x - mean) * r * ga.x + ba.x), f2bf((v0.y - mean) * r * ga.y + ba.y),
             f2bf((v0.z - mean) * r * ga.z + ba.z), f2bf((v0.w - mean) * r * ga.w + ba.w) };
  us4 o1 = { f2bf((v1.x - mean) * r * gb.x + bb.x), f2bf((v1.y - mean) * r * gb.y + bb.y),
             f2bf((v1.z - mean) * r * gb.z + bb.z), f2bf((v1.w - mean) * r * gb.w + bb.w) };
  *(us4*)(out + (size_t)tok * 512 + lane * 4) = o0;
  *(us4*)(out + (size_t)tok * 512 + 256 + lane * 4) = o1;
}

// ---------------- weight transpose + cast ----------------
// wqkvT[n][k] = w_qkv[k][n] (bf16), woutT[n][k] = w_out[k][n] (bf16)
__global__ void prep_w_kernel(const float* __restrict__ wqkv, const float* __restrict__ wout,
                              u16* __restrict__ wqkvT, u16* __restrict__ woutT) {
  int idx = blockIdx.x * blockDim.x + threadIdx.x;
  if (idx < 512 * 1536) {
    int n = idx >> 9, k = idx & 511;
    wqkvT[idx] = f2bf(wqkv[k * 1536 + n]);
  } else {
    int j = idx - 512 * 1536;
    if (j < 512 * 512) {
      int n = j >> 9, k = j & 511;
      woutT[j] = f2bf(wout[k * 512 + n]);
    }
  }
}

// ---------------- DPB MLP: 289 rows, one block (128 threads) per row ----------------
__device__ __forceinline__ float lnrelu128(float a, float g, float* red, int tid) {
  float s = a, q = a * a;
#pragma unroll
  for (int m = 1; m < 64; m <<= 1) { s += __shfl_xor(s, m, 64); q += __shfl_xor(q, m, 64); }
  __syncthreads();
  if ((tid & 63) == 0) { red[tid >> 6] = s; red[2 + (tid >> 6)] = q; }
  __syncthreads();
  float S = red[0] + red[1], Q = red[2] + red[3];
  float mean = S * (1.f / 128.f);
  float var = Q * (1.f / 128.f) - mean * mean;
  float y = (a - mean) * rsqrtf(var + 1e-5f) * g;
  return fmaxf(y, 0.f);
}

__global__ void dpb_mlp_kernel(const float* __restrict__ w0, const float* __restrict__ b0, const float* __restrict__ g0,
                               const float* __restrict__ w1, const float* __restrict__ b1, const float* __restrict__ g1,
                               const float* __restrict__ w2, const float* __restrict__ b2, const float* __restrict__ g2,
                               const float* __restrict__ w3, const float* __restrict__ b3,
                               float* __restrict__ biases) {
  __shared__ float h[128];
  __shared__ float red[4];
  const int tid = threadIdx.x;
  const int row = blockIdx.x;
  const float p0 = (float)(row / 17) - 8.0f;
  const float p1 = (float)(row % 17) - 8.0f;
  float a = p0 * w0[tid] + p1 * w0[128 + tid] + b0[tid];
  a = lnrelu128(a, g0[tid], red, tid);
  h[tid] = a;
  __syncthreads();
  float acc = b1[tid];
  for (int i = 0; i < 128; ++i) acc += h[i] * w1[i * 128 + tid];
  acc = lnrelu128(acc, g1[tid], red, tid);  // internal barriers also fence h reads
  h[tid] = acc;
  __syncthreads();
  float acc2 = b2[tid];
  for (int i = 0; i < 128; ++i) acc2 += h[i] * w2[i * 128 + tid];
  acc2 = lnrelu128(acc2, g2[tid], red, tid);
  float t = acc2 * w3[tid];
#pragma unroll
  for (int m = 1; m < 64; m <<= 1) t += __shfl_xor(t, m, 64);
  __syncthreads();
  if ((tid & 63) == 0) red[tid >> 6] = t;
  __syncthreads();
  if (tid == 0) biases[row] = red[0] + red[1] + b3[0];
}

// table[i*64+j] = biases[(s1i-s1j+7)*15 + (s2i-s2j+7)]
__global__ void dpb_table_kernel(const float* __restrict__ biases, float* __restrict__ table) {
  int t = blockIdx.x * blockDim.x + threadIdx.x;
  if (t < 4096) {
    int i = t >> 6, j = t & 63;
    int r0 = (i >> 3) - (j >> 3) + 7;
    int r1 = (i & 7) - (j & 7) + 7;
    table[t] = biases[r0 * 15 + r1];
  }
}

// ---------------- bf16 GEMM, C[M,N] = A[M,512] * B[512,N], B given as BT[N,512] ----------------
// 128x128 tile, BK=32, 4 waves each 64x64 (4x4 16x16x32 fragments). m97 structure +
// XOR chunk swizzle (phys chunk = logical ^ (row&3)) to cut ds_read_b128 bank conflicts.
template <int N, bool F32OUT>
__global__ __launch_bounds__(256) void gemm_bt_kernel(const u16* __restrict__ A, const u16* __restrict__ BT,
                                                      void* __restrict__ Cv, const float* __restrict__ bias) {
  __shared__ __align__(16) u16 As[128 * 32];
  __shared__ __align__(16) u16 Bs[128 * 32];
  const int tid = threadIdx.x;
  const int w = tid >> 6, l = tid & 63;
  const int wr = w >> 1, wc = w & 1;
  const int cr = l & 15, cg = l >> 4;
  const size_t brow = (size_t)blockIdx.x * 128;
  const int bcol = blockIdx.y * 128;

  const f32x4 zero = {0.f, 0.f, 0.f, 0.f};
  f32x4 acc[4][4];
#pragma unroll
  for (int i = 0; i < 4; ++i)
#pragma unroll
    for (int j = 0; j < 4; ++j) acc[i][j] = zero;

  const int srow = l >> 2;                         // row within 16-row chunk
  const int scol = ((l & 3) ^ (srow & 3)) * 8;     // pre-swizzled source column
  const u16* gA0 = A + (brow + (size_t)w * 32 + srow) * 512 + scol;
  const u16* gB0 = BT + ((size_t)bcol + w * 32 + srow) * 512 + scol;
  u16* lA0 = &As[w * 1024];
  u16* lA1 = &As[w * 1024 + 512];
  u16* lB0 = &Bs[w * 1024];
  u16* lB1 = &Bs[w * 1024 + 512];

  for (int k0 = 0; k0 < 512; k0 += 32) {
    gload_lds16(gA0 + k0, lA0);
    gload_lds16(gA0 + k0 + 16 * 512, lA1);
    gload_lds16(gB0 + k0, lB0);
    gload_lds16(gB0 + k0 + 16 * 512, lB1);
    __syncthreads();
    short8 af[4], bf[4];
#pragma unroll
    for (int mt = 0; mt < 4; ++mt) {
      int r = wr * 64 + mt * 16 + cr;
      af[mt] = *(const short8*)&As[r * 32 + ((cg ^ (r & 3)) * 8)];
    }
#pragma unroll
    for (int nt = 0; nt < 4; ++nt) {
      int r = wc * 64 + nt * 16 + cr;
      bf[nt] = *(const short8*)&Bs[r * 32 + ((cg ^ (r & 3)) * 8)];
    }
#pragma unroll
    for (int mt = 0; mt < 4; ++mt)
#pragma unroll
      for (int nt = 0; nt < 4; ++nt)
        acc[mt][nt] = __builtin_amdgcn_mfma_f32_16x16x32_bf16(af[mt], bf[nt], acc[mt][nt], 0, 0, 0);
    __syncthreads();
  }

  if (F32OUT) {
    float* C = (float*)Cv;
#pragma unroll
    for (int nt = 0; nt < 4; ++nt) {
      int col = bcol + wc * 64 + nt * 16 + cr;
      float bv = bias[col];
#pragma unroll
      for (int mt = 0; mt < 4; ++mt)
#pragma unroll
        for (int reg = 0; reg < 4; ++reg) {
          size_t r = brow + wr * 64 + mt * 16 + cg * 4 + reg;
          C[r * N + col] = acc[mt][nt][reg] + bv;
        }
    }
  } else {
    u16* C = (u16*)Cv;
#pragma unroll
    for (int nt = 0; nt < 4; ++nt) {
      int col = bcol + wc * 64 + nt * 16 + cr;
#pragma unroll
      for (int mt = 0; mt < 4; ++mt)
#pragma unroll
        for (int reg = 0; reg < 4; ++reg) {
          size_t r = brow + wr * 64 + mt * 16 + cg * 4 + reg;
          C[r * N + col] = f2bf(acc[mt][nt][reg]);
        }
    }
  }
}

// ---------------- windowed attention: one wave per (window, head) ----------------
// qkv is chunk-local token-major [16384][1536] bf16 (q|k|v each 512 = 16 heads x 32).
__global__ __launch_bounds__(64) void attn_kernel(const u16* __restrict__ qkv,
                                                  const float* __restrict__ table,
                                                  u16* __restrict__ aout) {
  __shared__ __align__(16) u16 P[64 * 72];
  __shared__ __align__(16) u16 VT[32 * 72];
  const int l = threadIdx.x;
  const int cr = l & 15, cg = l >> 4;
  const int head = blockIdx.x & 15;
  const int win = blockIdx.x >> 4;
  // chunk-local base row: b_local*4096 + wy*512 + wx*8
  const int base = ((win >> 6) << 12) + (((win >> 3) & 7) << 9) + ((win & 7) << 3);

  // stage V^T: lane = token, 32 dh values -> VT[d][token]
  {
    const size_t row = base + ((l >> 3) << 6) + (l & 7);
    const u16* vp = qkv + row * 1536 + 1024 + head * 32;
    short8 v0 = *(const short8*)(vp);
    short8 v1 = *(const short8*)(vp + 8);
    short8 v2 = *(const short8*)(vp + 16);
    short8 v3 = *(const short8*)(vp + 24);
#pragma unroll
    for (int j = 0; j < 8; ++j) {
      VT[j * 72 + l] = (u16)v0[j];
      VT[(8 + j) * 72 + l] = (u16)v1[j];
      VT[(16 + j) * 72 + l] = (u16)v2[j];
      VT[(24 + j) * 72 + l] = (u16)v3[j];
    }
  }

  short8 qf[4], kf[4];
#pragma unroll
  for (int mt = 0; mt < 4; ++mt) {
    int t = mt * 16 + cr;
    size_t row = base + ((t >> 3) << 6) + (t & 7);
    qf[mt] = *(const short8*)(qkv + row * 1536 + head * 32 + cg * 8);
    kf[mt] = *(const short8*)(qkv + row * 1536 + 512 + head * 32 + cg * 8);
  }

  const f32x4 zero = {0.f, 0.f, 0.f, 0.f};
  f32x4 s[4][4];
#pragma unroll
  for (int mt = 0; mt < 4; ++mt)
#pragma unroll
    for (int nt = 0; nt < 4; ++nt)
      s[mt][nt] = __builtin_amdgcn_mfma_f32_16x16x32_bf16(qf[mt], kf[nt], zero, 0, 0, 0);

  const float scale = 0.17677669529663689f;  // 32^-0.5
#pragma unroll
  for (int mt = 0; mt < 4; ++mt) {
#pragma unroll
    for (int reg = 0; reg < 4; ++reg) {
      const int r = mt * 16 + cg * 4 + reg;
      float v[4];
      float mx = -3.0e38f;
#pragma unroll
      for (int nt = 0; nt < 4; ++nt) {
        v[nt] = s[mt][nt][reg] * scale + table[r * 64 + nt * 16 + cr];
        mx = fmaxf(mx, v[nt]);
      }
#pragma unroll
      for (int m2 = 1; m2 < 16; m2 <<= 1) mx = fmaxf(mx, __shfl_xor(mx, m2, 64));
      float sum = 0.f;
#pragma unroll
      for (int nt = 0; nt < 4; ++nt) { v[nt] = __expf(v[nt] - mx); sum += v[nt]; }
#pragma unroll
      for (int m2 = 1; m2 < 16; m2 <<= 1) sum += __shfl_xor(sum, m2, 64);
      float inv = 1.0f / sum;
#pragma unroll
      for (int nt = 0; nt < 4; ++nt) P[r * 72 + nt * 16 + cr] = f2bf(v[nt] * inv);
    }
  }
  __syncthreads();

  f32x4 o[4][2];
#pragma unroll
  for (int mt = 0; mt < 4; ++mt) { o[mt][0] = zero; o[mt][1] = zero; }
#pragma unroll
  for (int kk = 0; kk < 2; ++kk) {
    short8 pf[4], vf[2];
#pragma unroll
    for (int mt = 0; mt < 4; ++mt) pf[mt] = *(const short8*)&P[(mt * 16 + cr) * 72 + kk * 32 + cg * 8];
#pragma unroll
    for (int n2 = 0; n2 < 2; ++n2) vf[n2] = *(const short8*)&VT[(n2 * 16 + cr) * 72 + kk * 32 + cg * 8];
#pragma unroll
    for (int mt = 0; mt < 4; ++mt)
#pragma unroll
      for (int n2 = 0; n2 < 2; ++n2)
        o[mt][n2] = __builtin_amdgcn_mfma_f32_16x16x32_bf16(pf[mt], vf[n2], o[mt][n2], 0, 0, 0);
  }

#pragma unroll
  for (int mt = 0; mt < 4; ++mt)
#pragma unroll
    for (int n2 = 0; n2 < 2; ++n2)
#pragma unroll
      for (int reg = 0; reg < 4; ++reg) {
        int t = mt * 16 + cg * 4 + reg;
        size_t row = base + ((t >> 3) << 6) + (t & 7);
        aout[row * 512 + head * 32 + n2 * 16 + cr] = f2bf(o[mt][n2][reg]);
      }
}

// ---------------- launch ----------------
extern "C" void kernel_launch(void* const* d_in, const int* in_sizes, int n_in,
                              void* d_out, int out_size, void* d_ws, size_t ws_size,
                              hipStream_t stream) {
  const float* x = (const float*)d_in[0];
  const float* norm_g = (const float*)d_in[1];
  const float* norm_b = (const float*)d_in[2];
  const float* w_qkv = (const float*)d_in[3];
  const float* w_out = (const float*)d_in[4];
  const float* b_out = (const float*)d_in[5];
  const float* dw0 = (const float*)d_in[6];
  const float* db0 = (const float*)d_in[7];
  const float* dg0 = (const float*)d_in[8];
  const float* dw1 = (const float*)d_in[9];
  const float* db1 = (const float*)d_in[10];
  const float* dg1 = (const float*)d_in[11];
  const float* dw2 = (const float*)d_in[12];
  const float* db2 = (const float*)d_in[13];
  const float* dg2 = (const float*)d_in[14];
  const float* dw3 = (const float*)d_in[15];
  const float* db3 = (const float*)d_in[16];

  char* ws = (char*)d_ws;
  u16* xln = (u16*)(ws);                    // 67,108,864 B  : bf16 LN'd x, token-major
  u16* wqkvT = (u16*)(ws + 67108864);       //  1,572,864 B  : [1536][512]
  u16* woutT = (u16*)(ws + 68681728);       //    524,288 B  : [512][512]
  float* biases = (float*)(ws + 69206016);  //      4,096 B
  float* table = (float*)(ws + 69210112);   //     16,384 B  : [64][64] f32
  u16* qkvbuf = (u16*)(ws + 69226496);      // 50,331,648 B  : chunk [16384][1536] bf16
  u16* attnbuf = (u16*)(ws + 119558144);    // 16,777,216 B  : chunk [16384][512] bf16
  // total ws use: 136,335,360 B

  ln_cast_kernel<<<16384, 256, 0, stream>>>(x, norm_g, norm_b, xln);
  prep_w_kernel<<<4096, 256, 0, stream>>>(w_qkv, w_out, wqkvT, woutT);
  dpb_mlp_kernel<<<289, 128, 0, stream>>>(dw0, db0, dg0, dw1, db1, dg1, dw2, db2, dg2, dw3, db3, biases);
  dpb_table_kernel<<<16, 256, 0, stream>>>(biases, table);

  for (int c = 0; c < 4; ++c) {
    const u16* Ac = xln + (size_t)c * 16384 * 512;
    gemm_bt_kernel<1536, false><<<dim3(128, 12), 256, 0, stream>>>(Ac, wqkvT, (void*)qkvbuf, nullptr);
    attn_kernel<<<4096, 64, 0, stream>>>(qkvbuf, table, attnbuf);
    float* Cc = (float*)d_out + (size_t)c * 16384 * 512;
    gemm_bt_kernel<512, true><<<dim3(128, 4), 256, 0, stream>>>(attnbuf, woutT, (void*)Cc, b_out);
  }
}

// Round 4
// 379.723 us; speedup vs baseline: 1.0919x; 1.0919x over previous
//
#include <hip/hip_runtime.h>
#include <cstdint>
#include <cstddef>

typedef unsigned short u16;
typedef __attribute__((ext_vector_type(8))) short short8;
typedef __attribute__((ext_vector_type(4))) float f32x4;
typedef __attribute__((ext_vector_type(4))) unsigned short us4;

#define AS1 __attribute__((address_space(1)))
#define AS3 __attribute__((address_space(3)))

__device__ __forceinline__ u16 f2bf(float f) {
  union { float f; unsigned u; } v; v.f = f;
  unsigned r = v.u + 0x7fffu + ((v.u >> 16) & 1u);
  return (u16)(r >> 16);
}

__device__ __forceinline__ void gload_lds16(const u16* g, u16* l) {
  __builtin_amdgcn_global_load_lds((AS1 void*)g, (AS3 void*)l, 16, 0, 0);
}

// ---------------- LayerNorm + cast to bf16 (token-major) ----------------
__global__ void ln_cast_kernel(const float* __restrict__ x, const float* __restrict__ g,
                               const float* __restrict__ b, u16* __restrict__ out) {
  const int lane = threadIdx.x & 63;
  const int tok = blockIdx.x * 4 + (threadIdx.x >> 6);
  const float4* row = (const float4*)(x + (size_t)tok * 512);
  float4 v0 = row[lane];
  float4 v1 = row[lane + 64];
  float s = v0.x + v0.y + v0.z + v0.w + v1.x + v1.y + v1.z + v1.w;
  float q = v0.x*v0.x + v0.y*v0.y + v0.z*v0.z + v0.w*v0.w
          + v1.x*v1.x + v1.y*v1.y + v1.z*v1.z + v1.w*v1.w;
#pragma unroll
  for (int m = 1; m < 64; m <<= 1) { s += __shfl_xor(s, m, 64); q += __shfl_xor(q, m, 64); }
  const float mean = s * (1.0f / 512.0f);
  const float var = q * (1.0f / 512.0f) - mean * mean;
  const float r = rsqrtf(var + 1e-5f);
  const float4* g4 = (const float4*)g;
  const float4* b4 = (const float4*)b;
  float4 ga = g4[lane], gb = g4[lane + 64];
  float4 ba = b4[lane], bb = b4[lane + 64];
  us4 o0 = { f2bf((v0.x - mean) * r * ga.x + ba.x), f2bf((v0.y - mean) * r * ga.y + ba.y),
             f2bf((v0.z - mean) * r * ga.z + ba.z), f2bf((v0.w - mean) * r * ga.w + ba.w) };
  us4 o1 = { f2bf((v1.x - mean) * r * gb.x + bb.x), f2bf((v1.y - mean) * r * gb.y + bb.y),
             f2bf((v1.z - mean) * r * gb.z + bb.z), f2bf((v1.w - mean) * r * gb.w + bb.w) };
  *(us4*)(out + (size_t)tok * 512 + lane * 4) = o0;
  *(us4*)(out + (size_t)tok * 512 + 256 + lane * 4) = o1;
}

// ---------------- weight transpose + cast ----------------
__global__ void prep_w_kernel(const float* __restrict__ wqkv, const float* __restrict__ wout,
                              u16* __restrict__ wqkvT, u16* __restrict__ woutT) {
  int idx = blockIdx.x * blockDim.x + threadIdx.x;
  if (idx < 512 * 1536) {
    int n = idx >> 9, k = idx & 511;
    wqkvT[idx] = f2bf(wqkv[k * 1536 + n]);
  } else {
    int j = idx - 512 * 1536;
    if (j < 512 * 512) {
      int n = j >> 9, k = j & 511;
      woutT[j] = f2bf(wout[k * 512 + n]);
    }
  }
}

// ---------------- DPB MLP ----------------
__device__ __forceinline__ float lnrelu128(float a, float g, float* red, int tid) {
  float s = a, q = a * a;
#pragma unroll
  for (int m = 1; m < 64; m <<= 1) { s += __shfl_xor(s, m, 64); q += __shfl_xor(q, m, 64); }
  __syncthreads();
  if ((tid & 63) == 0) { red[tid >> 6] = s; red[2 + (tid >> 6)] = q; }
  __syncthreads();
  float S = red[0] + red[1], Q = red[2] + red[3];
  float mean = S * (1.f / 128.f);
  float var = Q * (1.f / 128.f) - mean * mean;
  float y = (a - mean) * rsqrtf(var + 1e-5f) * g;
  return fmaxf(y, 0.f);
}

__global__ void dpb_mlp_kernel(const float* __restrict__ w0, const float* __restrict__ b0, const float* __restrict__ g0,
                               const float* __restrict__ w1, const float* __restrict__ b1, const float* __restrict__ g1,
                               const float* __restrict__ w2, const float* __restrict__ b2, const float* __restrict__ g2,
                               const float* __restrict__ w3, const float* __restrict__ b3,
                               float* __restrict__ biases) {
  __shared__ float h[128];
  __shared__ float red[4];
  const int tid = threadIdx.x;
  const int row = blockIdx.x;
  const float p0 = (float)(row / 17) - 8.0f;
  const float p1 = (float)(row % 17) - 8.0f;
  float a = p0 * w0[tid] + p1 * w0[128 + tid] + b0[tid];
  a = lnrelu128(a, g0[tid], red, tid);
  h[tid] = a;
  __syncthreads();
  float acc = b1[tid];
  for (int i = 0; i < 128; ++i) acc += h[i] * w1[i * 128 + tid];
  acc = lnrelu128(acc, g1[tid], red, tid);
  h[tid] = acc;
  __syncthreads();
  float acc2 = b2[tid];
  for (int i = 0; i < 128; ++i) acc2 += h[i] * w2[i * 128 + tid];
  acc2 = lnrelu128(acc2, g2[tid], red, tid);
  float t = acc2 * w3[tid];
#pragma unroll
  for (int m = 1; m < 64; m <<= 1) t += __shfl_xor(t, m, 64);
  __syncthreads();
  if ((tid & 63) == 0) red[tid >> 6] = t;
  __syncthreads();
  if (tid == 0) biases[row] = red[0] + red[1] + b3[0];
}

__global__ void dpb_table_kernel(const float* __restrict__ biases, float* __restrict__ table) {
  int t = blockIdx.x * blockDim.x + threadIdx.x;
  if (t < 4096) {
    int i = t >> 6, j = t & 63;
    int r0 = (i >> 3) - (j >> 3) + 7;
    int r1 = (i & 7) - (j & 7) + 7;
    table[t] = biases[r0 * 15 + r1];
  }
}

// ---------------- 256x256x64 8-phase bf16 GEMM (K=512, B passed as BT[N][512]) ----------------
// LDS layout per operand: [2 buf][2 ksub][256 rows][32 cols] bf16, 16B chunks XOR-swizzled:
// phys_chunk = logical_chunk ^ ((row + (row>>2)) & 3)  (lane-constant on the read side).
// Staging writes LDS linearly (global_load_lds) with pre-swizzled global source.
// ROUND-4 FIX: bP previously included the +32768 B-base AND added bbase (which also
// includes 32768) at each read -> all B fragments read lds[65536+...], past the end of
// the allocation (undefined data: NaN in r2, zeros in r3). Base now added exactly once.
template <int CT, bool F32OUT>
__global__ __launch_bounds__(512, 2) void gemm256_kernel(const u16* __restrict__ A, const u16* __restrict__ BT,
                                                         void* __restrict__ Cv, const float* __restrict__ bias) {
  __shared__ __align__(16) u16 lds[65536];  // A: [0,32768), B: [32768,65536)
  const int tid = threadIdx.x;
  const int w = tid >> 6, l = tid & 63;
  const int wm = w >> 2, wn = w & 3;
  const int cr = l & 15, cg = l >> 4;
  const int pc8 = (cg ^ ((cr + (cr >> 2)) & 3)) * 8;

  // XCD-aware bijective swizzle (gridDim.x % 8 == 0 in all our launches)
  const int nwg = gridDim.x;
  const int q = nwg >> 3;
  const int swz = (blockIdx.x & 7) * q + (blockIdx.x >> 3);
  const int rt = swz / CT, ct = swz % CT;
  const size_t brow = (size_t)rt * 256;
  const size_t bcol = (size_t)ct * 256;
  const int N = CT * 256;

  // stage-side constants
  const int srow = tid >> 2;
  const int sch8 = ((tid & 3) ^ ((srow + (srow >> 2)) & 3)) * 8;

  const f32x4 zero = {0.f, 0.f, 0.f, 0.f};
  f32x4 acc[8][4];
#pragma unroll
  for (int i = 0; i < 8; ++i)
#pragma unroll
    for (int j = 0; j < 4; ++j) acc[i][j] = zero;

  const u16* aP = &lds[(wm * 128 + cr) * 32 + pc8];           // + abase (cur*16384) at read
  const u16* bP = &lds[(wn * 64 + cr) * 32 + pc8];            // + bbase (32768 + cur*16384) at read

  // stage one half-tile (256 rows x 32 cols) = 2 x (512 threads x 16B)
#define STAGE_HALF(G, GROW0, KCOL, LBASE)                                          \
  do {                                                                             \
    const u16* g0_ = (G) + ((GROW0) + srow) * 512 + (KCOL) + sch8;                 \
    gload_lds16(g0_, &lds[(LBASE) + w * 512]);                                     \
    gload_lds16(g0_ + 128 * 512, &lds[(LBASE) + 4096 + w * 512]);                  \
  } while (0)

  // prologue: stage K-tile 0 (A0,B0,A1,B1) into buf0
  STAGE_HALF(A, brow, 0, 0);
  STAGE_HALF(BT, bcol, 0, 32768);
  STAGE_HALF(A, brow, 32, 8192);
  STAGE_HALF(BT, bcol, 32, 32768 + 8192);
  asm volatile("s_waitcnt vmcnt(4)" ::: "memory");
  __builtin_amdgcn_s_barrier();
  __builtin_amdgcn_sched_barrier(0);

#pragma unroll 2
  for (int kt = 0; kt < 8; ++kt) {
    const int cur = kt & 1;
    const int nbuf = cur ^ 1;
    const int ktn = (kt < 7) ? kt + 1 : 7;   // kt==7 re-stages itself into the dead buffer (keeps vmcnt uniform)
    const int kcn = ktn * 64;
    const int abase = cur * 16384;
    const int bbase = 32768 + cur * 16384;
    short8 af[8], bfr[2];

    // ---- phase 0: ksub0, B-cols 0-1
#pragma unroll
    for (int fr = 0; fr < 8; ++fr) af[fr] = *(const short8*)(aP + abase + fr * 512);
#pragma unroll
    for (int c = 0; c < 2; ++c) bfr[c] = *(const short8*)(bP + bbase + c * 512);
    STAGE_HALF(A, brow, kcn, nbuf * 16384);
    __builtin_amdgcn_s_barrier();
    __builtin_amdgcn_sched_barrier(0);
    __builtin_amdgcn_s_setprio(1);
#pragma unroll
    for (int fr = 0; fr < 8; ++fr) {
      acc[fr][0] = __builtin_amdgcn_mfma_f32_16x16x32_bf16(af[fr], bfr[0], acc[fr][0], 0, 0, 0);
      acc[fr][1] = __builtin_amdgcn_mfma_f32_16x16x32_bf16(af[fr], bfr[1], acc[fr][1], 0, 0, 0);
    }
    __builtin_amdgcn_s_setprio(0);
    __builtin_amdgcn_s_barrier();
    __builtin_amdgcn_sched_barrier(0);

    // ---- phase 1: ksub0, B-cols 2-3
#pragma unroll
    for (int c = 0; c < 2; ++c) bfr[c] = *(const short8*)(bP + bbase + (2 + c) * 512);
    STAGE_HALF(BT, bcol, kcn, 32768 + nbuf * 16384);
    __builtin_amdgcn_s_barrier();
    __builtin_amdgcn_sched_barrier(0);
    __builtin_amdgcn_s_setprio(1);
#pragma unroll
    for (int fr = 0; fr < 8; ++fr) {
      acc[fr][2] = __builtin_amdgcn_mfma_f32_16x16x32_bf16(af[fr], bfr[0], acc[fr][2], 0, 0, 0);
      acc[fr][3] = __builtin_amdgcn_mfma_f32_16x16x32_bf16(af[fr], bfr[1], acc[fr][3], 0, 0, 0);
    }
    __builtin_amdgcn_s_setprio(0);
    asm volatile("s_waitcnt vmcnt(4)" ::: "memory");  // A1,B1 of current K-tile have landed
    __builtin_amdgcn_s_barrier();
    __builtin_amdgcn_sched_barrier(0);

    // ---- phase 2: ksub1, B-cols 0-1
#pragma unroll
    for (int fr = 0; fr < 8; ++fr) af[fr] = *(const short8*)(aP + abase + 8192 + fr * 512);
#pragma unroll
    for (int c = 0; c < 2; ++c) bfr[c] = *(const short8*)(bP + bbase + 8192 + c * 512);
    STAGE_HALF(A, brow, kcn + 32, nbuf * 16384 + 8192);
    __builtin_amdgcn_s_barrier();
    __builtin_amdgcn_sched_barrier(0);
    __builtin_amdgcn_s_setprio(1);
#pragma unroll
    for (int fr = 0; fr < 8; ++fr) {
      acc[fr][0] = __builtin_amdgcn_mfma_f32_16x16x32_bf16(af[fr], bfr[0], acc[fr][0], 0, 0, 0);
      acc[fr][1] = __builtin_amdgcn_mfma_f32_16x16x32_bf16(af[fr], bfr[1], acc[fr][1], 0, 0, 0);
    }
    __builtin_amdgcn_s_setprio(0);
    __builtin_amdgcn_s_barrier();
    __builtin_amdgcn_sched_barrier(0);

    // ---- phase 3: ksub1, B-cols 2-3
#pragma unroll
    for (int c = 0; c < 2; ++c) bfr[c] = *(const short8*)(bP + bbase + 8192 + (2 + c) * 512);
    STAGE_HALF(BT, bcol, kcn + 32, 32768 + nbuf * 16384 + 8192);
    __builtin_amdgcn_s_barrier();
    __builtin_amdgcn_sched_barrier(0);
    __builtin_amdgcn_s_setprio(1);
#pragma unroll
    for (int fr = 0; fr < 8; ++fr) {
      acc[fr][2] = __builtin_amdgcn_mfma_f32_16x16x32_bf16(af[fr], bfr[0], acc[fr][2], 0, 0, 0);
      acc[fr][3] = __builtin_amdgcn_mfma_f32_16x16x32_bf16(af[fr], bfr[1], acc[fr][3], 0, 0, 0);
    }
    __builtin_amdgcn_s_setprio(0);
    asm volatile("s_waitcnt vmcnt(4)" ::: "memory");  // A0,B0 of next K-tile have landed
    __builtin_amdgcn_s_barrier();
    __builtin_amdgcn_sched_barrier(0);
  }
#undef STAGE_HALF

  // Drain ALL outstanding LDS-DMA before the wave can retire: pending
  // global_load_lds at s_endpgm would land in a reallocated block's LDS.
  asm volatile("s_waitcnt vmcnt(0)" ::: "memory");
  __builtin_amdgcn_sched_barrier(0);

  // epilogue
  if (F32OUT) {
    float* C = (float*)Cv;
#pragma unroll
    for (int fc = 0; fc < 4; ++fc) {
      size_t col = bcol + wn * 64 + fc * 16 + cr;
      float bv = bias[col];
#pragma unroll
      for (int fr = 0; fr < 8; ++fr)
#pragma unroll
        for (int reg = 0; reg < 4; ++reg) {
          size_t r = brow + wm * 128 + fr * 16 + cg * 4 + reg;
          C[r * N + col] = acc[fr][fc][reg] + bv;
        }
    }
  } else {
    u16* C = (u16*)Cv;
#pragma unroll
    for (int fc = 0; fc < 4; ++fc) {
      size_t col = bcol + wn * 64 + fc * 16 + cr;
#pragma unroll
      for (int fr = 0; fr < 8; ++fr)
#pragma unroll
        for (int reg = 0; reg < 4; ++reg) {
          size_t r = brow + wm * 128 + fr * 16 + cg * 4 + reg;
          C[r * N + col] = f2bf(acc[fr][fc][reg]);
        }
    }
  }
}

// ---------------- windowed attention: one wave per (window, head) ----------------
__global__ __launch_bounds__(64) void attn_kernel(const u16* __restrict__ qkv,
                                                  const float* __restrict__ table,
                                                  u16* __restrict__ aout) {
  __shared__ __align__(16) u16 P[64 * 72];
  __shared__ __align__(16) u16 VT[32 * 72];
  const int l = threadIdx.x;
  const int cr = l & 15, cg = l >> 4;
  const int head = blockIdx.x & 15;
  const int win = blockIdx.x >> 4;
  const int base = ((win >> 6) << 12) + (((win >> 3) & 7) << 9) + ((win & 7) << 3);

  {
    const size_t row = base + ((l >> 3) << 6) + (l & 7);
    const u16* vp = qkv + row * 1536 + 1024 + head * 32;
    short8 v0 = *(const short8*)(vp);
    short8 v1 = *(const short8*)(vp + 8);
    short8 v2 = *(const short8*)(vp + 16);
    short8 v3 = *(const short8*)(vp + 24);
#pragma unroll
    for (int j = 0; j < 8; ++j) {
      VT[j * 72 + l] = (u16)v0[j];
      VT[(8 + j) * 72 + l] = (u16)v1[j];
      VT[(16 + j) * 72 + l] = (u16)v2[j];
      VT[(24 + j) * 72 + l] = (u16)v3[j];
    }
  }

  short8 qf[4], kf[4];
#pragma unroll
  for (int mt = 0; mt < 4; ++mt) {
    int t = mt * 16 + cr;
    size_t row = base + ((t >> 3) << 6) + (t & 7);
    qf[mt] = *(const short8*)(qkv + row * 1536 + head * 32 + cg * 8);
    kf[mt] = *(const short8*)(qkv + row * 1536 + 512 + head * 32 + cg * 8);
  }

  const f32x4 zero = {0.f, 0.f, 0.f, 0.f};
  f32x4 s[4][4];
#pragma unroll
  for (int mt = 0; mt < 4; ++mt)
#pragma unroll
    for (int nt = 0; nt < 4; ++nt)
      s[mt][nt] = __builtin_amdgcn_mfma_f32_16x16x32_bf16(qf[mt], kf[nt], zero, 0, 0, 0);

  const float scale = 0.17677669529663689f;
#pragma unroll
  for (int mt = 0; mt < 4; ++mt) {
#pragma unroll
    for (int reg = 0; reg < 4; ++reg) {
      const int r = mt * 16 + cg * 4 + reg;
      float v[4];
      float mx = -3.0e38f;
#pragma unroll
      for (int nt = 0; nt < 4; ++nt) {
        v[nt] = s[mt][nt][reg] * scale + table[r * 64 + nt * 16 + cr];
        mx = fmaxf(mx, v[nt]);
      }
#pragma unroll
      for (int m2 = 1; m2 < 16; m2 <<= 1) mx = fmaxf(mx, __shfl_xor(mx, m2, 64));
      float sum = 0.f;
#pragma unroll
      for (int nt = 0; nt < 4; ++nt) { v[nt] = __expf(v[nt] - mx); sum += v[nt]; }
#pragma unroll
      for (int m2 = 1; m2 < 16; m2 <<= 1) sum += __shfl_xor(sum, m2, 64);
      float inv = 1.0f / sum;
#pragma unroll
      for (int nt = 0; nt < 4; ++nt) P[r * 72 + nt * 16 + cr] = f2bf(v[nt] * inv);
    }
  }
  __syncthreads();

  f32x4 o[4][2];
#pragma unroll
  for (int mt = 0; mt < 4; ++mt) { o[mt][0] = zero; o[mt][1] = zero; }
#pragma unroll
  for (int kk = 0; kk < 2; ++kk) {
    short8 pf[4], vf[2];
#pragma unroll
    for (int mt = 0; mt < 4; ++mt) pf[mt] = *(const short8*)&P[(mt * 16 + cr) * 72 + kk * 32 + cg * 8];
#pragma unroll
    for (int n2 = 0; n2 < 2; ++n2) vf[n2] = *(const short8*)&VT[(n2 * 16 + cr) * 72 + kk * 32 + cg * 8];
#pragma unroll
    for (int mt = 0; mt < 4; ++mt)
#pragma unroll
      for (int n2 = 0; n2 < 2; ++n2)
        o[mt][n2] = __builtin_amdgcn_mfma_f32_16x16x32_bf16(pf[mt], vf[n2], o[mt][n2], 0, 0, 0);
  }

#pragma unroll
  for (int mt = 0; mt < 4; ++mt)
#pragma unroll
    for (int n2 = 0; n2 < 2; ++n2)
#pragma unroll
      for (int reg = 0; reg < 4; ++reg) {
        int t = mt * 16 + cg * 4 + reg;
        size_t row = base + ((t >> 3) << 6) + (t & 7);
        aout[row * 512 + head * 32 + n2 * 16 + cr] = f2bf(o[mt][n2][reg]);
      }
}

// ---------------- launch ----------------
extern "C" void kernel_launch(void* const* d_in, const int* in_sizes, int n_in,
                              void* d_out, int out_size, void* d_ws, size_t ws_size,
                              hipStream_t stream) {
  const float* x = (const float*)d_in[0];
  const float* norm_g = (const float*)d_in[1];
  const float* norm_b = (const float*)d_in[2];
  const float* w_qkv = (const float*)d_in[3];
  const float* w_out = (const float*)d_in[4];
  const float* b_out = (const float*)d_in[5];
  const float* dw0 = (const float*)d_in[6];
  const float* db0 = (const float*)d_in[7];
  const float* dg0 = (const float*)d_in[8];
  const float* dw1 = (const float*)d_in[9];
  const float* db1 = (const float*)d_in[10];
  const float* dg1 = (const float*)d_in[11];
  const float* dw2 = (const float*)d_in[12];
  const float* db2 = (const float*)d_in[13];
  const float* dg2 = (const float*)d_in[14];
  const float* dw3 = (const float*)d_in[15];
  const float* db3 = (const float*)d_in[16];

  char* ws = (char*)d_ws;
  size_t off = 0;
  auto take = [&](size_t bytes) { char* p = ws + off; off += (bytes + 255) & ~(size_t)255; return p; };
  u16* xln = (u16*)take(65536ull * 512 * 2);
  u16* wqkvT = (u16*)take(1536 * 512 * 2);
  u16* woutT = (u16*)take(512 * 512 * 2);
  float* biases = (float*)take(289 * 4);
  float* table = (float*)take(4096 * 4);

  // pick largest chunk layout that fits the workspace
  size_t rem = (ws_size > off) ? ws_size - off : 0;
  int nch = 4;
  if (rem >= 65536ull * 2048 * 2 + 512) nch = 1;
  else if (rem >= 32768ull * 2048 * 2 + 512) nch = 2;
  const int rows = 65536 / nch;
  u16* qkvbuf = (u16*)take((size_t)rows * 1536 * 2);
  u16* attnbuf = (u16*)take((size_t)rows * 512 * 2);

  ln_cast_kernel<<<16384, 256, 0, stream>>>(x, norm_g, norm_b, xln);
  prep_w_kernel<<<4096, 256, 0, stream>>>(w_qkv, w_out, wqkvT, woutT);
  dpb_mlp_kernel<<<289, 128, 0, stream>>>(dw0, db0, dg0, dw1, db1, dg1, dw2, db2, dg2, dw3, db3, biases);
  dpb_table_kernel<<<16, 256, 0, stream>>>(biases, table);

  for (int c = 0; c < nch; ++c) {
    const u16* Ac = xln + (size_t)c * rows * 512;
    gemm256_kernel<6, false><<<(rows / 256) * 6, 512, 0, stream>>>(Ac, wqkvT, (void*)qkvbuf, nullptr);
    attn_kernel<<<(rows / 64) * 16, 64, 0, stream>>>(qkvbuf, table, attnbuf);
    float* Cc = (float*)d_out + (size_t)c * rows * 512;
    gemm256_kernel<2, true><<<(rows / 256) * 2, 512, 0, stream>>>(attnbuf, woutT, (void*)Cc, b_out);
  }
}